// Round 7
// baseline (193.468 us; speedup 1.0000x reference)
//
#include <hip/hip_runtime.h>
#include <math.h>

namespace {
typedef unsigned short u16;
typedef __attribute__((ext_vector_type(4))) float f32x4;
typedef __attribute__((ext_vector_type(8))) short bf16x8;

constexpr int kB  = 16;
constexpr int kC  = 256;
constexpr int kM  = 1024;

__device__ inline u16 f2b(float f) {
    union { float f; unsigned u; } un; un.f = f;
    unsigned r = un.u + 0x7FFF + ((un.u >> 16) & 1);
    return (u16)(r >> 16);
}
__device__ inline float b2f(u16 u) {
    union { unsigned u; float f; } un; un.u = ((unsigned)u) << 16; return un.f;
}

// ---------------------------------------------------------------------------
// K0: blocks 0..8: pack W (BN folded) -> Wb bf16 [144][256], bias bb f32
//     blocks 9..71: rpe f32 [63][63][16] -> rpe_b bf16 [63dr][64dc][32k]
// ---------------------------------------------------------------------------
__global__ __launch_bounds__(256) void k_prep(
    const float* __restrict__ Wq, const float* __restrict__ Wk,
    const float* __restrict__ Wv,
    const float* __restrict__ gq, const float* __restrict__ bq,
    const float* __restrict__ mq, const float* __restrict__ vq,
    const float* __restrict__ gv, const float* __restrict__ bv,
    const float* __restrict__ mv, const float* __restrict__ vv,
    const float* __restrict__ rpe,
    u16* __restrict__ Wb, float* __restrict__ bb, u16* __restrict__ rpe_b)
{
    const int bid = blockIdx.x;
    const int t = threadIdx.x;
    if (bid < 9) {
        const int oc = bid * 16 + (t >> 4);
        const int c0 = (t & 15) * 16;
        float s, bias;
        const float* wrow;
        if (oc < 64)      { float inv = rsqrtf(vq[oc] + 1e-5f); s = inv * gq[oc]; bias = bq[oc] - mq[oc] * s; wrow = Wq + (size_t)oc * kC; }
        else if (oc < 80) { s = 1.f; bias = 0.f; wrow = Wk + (size_t)(oc - 64) * kC; }
        else              { int i2 = oc - 80; float inv = rsqrtf(vv[i2] + 1e-5f); s = inv * gv[i2]; bias = bv[i2] - mv[i2] * s; wrow = Wv + (size_t)i2 * kC; }
#pragma unroll
        for (int cc = 0; cc < 16; ++cc)
            Wb[(size_t)oc * kC + c0 + cc] = f2b(wrow[c0 + cc] * s);
        if (c0 == 0) bb[oc] = bias;
    } else {
        const int dr = bid - 9;
        for (int e = t; e < 2048; e += 256) {
            int dc = e >> 5, k = e & 31;
            float v = (dc < 63 && k < 16) ? rpe[((size_t)dr * 63 + dc) * 16 + k] : 0.f;
            rpe_b[((size_t)dr * 64 + dc) * 32 + k] = f2b(v);
        }
    }
}

// ---------------------------------------------------------------------------
// K1 (MFMA): conv1x1, 16-m tiles.  grid (64 mtile, 16 b), block 256 (4 waves)
// waves own oc-tiles: w0:{0,1,2}=Q012, w1:{3,4}=Q3,K, w2:{5,6}=V01, w3:{7,8}=V23
// ---------------------------------------------------------------------------
__global__ __launch_bounds__(256) void k_qkv(
    const float* __restrict__ x, const u16* __restrict__ Wb,
    const float* __restrict__ bb,
    u16* __restrict__ Qb, float* __restrict__ Kf, u16* __restrict__ Vb)
{
    __shared__ float Xs[256][18];   // 18.4 KB -> 4+ blocks/CU

    const int b  = blockIdx.y;
    const int m0 = blockIdx.x * 16;
    const int t  = threadIdx.x;
    const int w  = t >> 6, lane = t & 63, li = lane & 15, lg = lane >> 4;

    // stage X tile [256c][16m] f32
#pragma unroll
    for (int j = 0; j < 4; ++j) {
        int e = t + 256 * j;
        int c = e >> 2, m4 = (e & 3) * 4;
        *(float4*)&Xs[c][m4] = *(const float4*)&x[(size_t)(b * kC + c) * kM + m0 + m4];
    }
    __syncthreads();

    const int nt = (w == 0) ? 3 : 2;
    const int t0 = (w == 0) ? 0 : 2 * w + 1;

    f32x4 acc[3];
#pragma unroll
    for (int i = 0; i < 3; ++i) acc[i] = (f32x4){0.f, 0.f, 0.f, 0.f};

    for (int ch = 0; ch < 8; ++ch) {
        const int c0 = ch * 32 + lg * 8;
        bf16x8 bfr;
#pragma unroll
        for (int j = 0; j < 8; ++j) bfr[j] = (short)f2b(Xs[c0 + j][li]);
        for (int i = 0; i < nt; ++i) {
            bf16x8 afr = *(const bf16x8*)&Wb[(size_t)((t0 + i) * 16 + li) * kC + c0];
            acc[i] = __builtin_amdgcn_mfma_f32_16x16x32_bf16(afr, bfr, acc[i], 0, 0, 0);
        }
    }

    const int m = m0 + li;
    for (int i = 0; i < nt; ++i) {
        const int tile = t0 + i;
        const int ocb = tile * 16 + lg * 4;
        float o[4];
#pragma unroll
        for (int reg = 0; reg < 4; ++reg) o[reg] = acc[i][reg] + bb[ocb + reg];
        if (tile < 4) {                       // Q tile: h=tile, k=lg*4+reg
            u16 pk[4];
#pragma unroll
            for (int reg = 0; reg < 4; ++reg) pk[reg] = f2b(o[reg]);
            u16* qp = Qb + ((size_t)(b * 4 + tile) * kM + m) * 32;
            *(uint2*)&qp[lg * 4] = *(const uint2*)pk;
            uint2 z; z.x = 0u; z.y = 0u;
            *(uint2*)&qp[16 + lg * 4] = z;
        } else if (tile == 4) {               // K f32
#pragma unroll
            for (int reg = 0; reg < 4; ++reg)
                Kf[(size_t)(b * 16 + lg * 4 + reg) * kM + m] = o[reg];
        } else {                              // V
            const int vb = (tile - 5) * 16 + lg * 4;
#pragma unroll
            for (int reg = 0; reg < 4; ++reg)
                Vb[(size_t)(b * 64 + vb + reg) * kM + m] = f2b(o[reg]);
        }
    }
}

// ---------------------------------------------------------------------------
// K2: sK = softmax_k(K); partial lam_c = sum_{m in blk} sK[m,k] V[m,v]
// grid (16 mb, 16 b), block 256.  lam_parts[mb][b][k][v]
// ---------------------------------------------------------------------------
__global__ __launch_bounds__(256) void k_lam(
    const float* __restrict__ Kf, const u16* __restrict__ Vb,
    float* __restrict__ lam_parts)
{
    __shared__ float Ks[16][64];
    __shared__ float Vsh[64][69];

    const int b = blockIdx.y, mb = blockIdx.x;
    const int m0 = mb * 64;
    const int t = threadIdx.x;
    const float* Kc = Kf + (size_t)b * 16 * kM + m0;
    const u16*   Vc = Vb + (size_t)b * 64 * kM + m0;

#pragma unroll
    for (int j = 0; j < 4; ++j) {
        int e = t + 256 * j;
        Ks[e >> 6][e & 63] = Kc[(size_t)(e >> 6) * kM + (e & 63)];
    }
#pragma unroll
    for (int j = 0; j < 4; ++j) {
        int e = t + 256 * j;
        int v = e >> 4, mq = (e & 15) * 4;
        uint2 pv = *(const uint2*)&Vc[(size_t)v * kM + mq];
        u16 pp[4]; *(uint2*)pp = pv;
#pragma unroll
        for (int i = 0; i < 4; ++i) Vsh[v][mq + i] = b2f(pp[i]);
    }
    __syncthreads();

    if (t < 64) {
        float vals[16];
        float mx = -1e30f;
#pragma unroll
        for (int k = 0; k < 16; ++k) { vals[k] = Ks[k][t]; mx = fmaxf(mx, vals[k]); }
        float sum = 0.f;
#pragma unroll
        for (int k = 0; k < 16; ++k) { vals[k] = __expf(vals[k] - mx); sum += vals[k]; }
        const float inv = 1.f / sum;
#pragma unroll
        for (int k = 0; k < 16; ++k) Ks[k][t] = vals[k] * inv;
    }
    __syncthreads();

    const int v = t & 63, kq = t >> 6;
    float a[4] = {0.f, 0.f, 0.f, 0.f};
#pragma unroll 4
    for (int mm = 0; mm < 64; ++mm) {
        const float vv_ = Vsh[v][mm];
#pragma unroll
        for (int j = 0; j < 4; ++j) a[j] += Ks[kq * 4 + j][mm] * vv_;
    }
    float* o = lam_parts + (size_t)(mb * kB + b) * 1024;
#pragma unroll
    for (int j = 0; j < 4; ++j) o[(kq * 4 + j) * 64 + v] = a[j];
}

// ---------------------------------------------------------------------------
// K3 (MFMA, barrier-free loop): out = Q@lam_c + position for 16 n-rows.
// grid (64 nblk, 16 b), block 256 = 4 waves = 4 heads.
// E and V fragments read directly from global (L2-resident); LDS only holds
// the per-wave S tile [nl][dc] (aligned b64 writes, u16 reads).
// ---------------------------------------------------------------------------
__global__ __launch_bounds__(256, 4) void k_attn(
    const u16* __restrict__ Qb, const u16* __restrict__ Vb,
    const u16* __restrict__ rpe_b, const float* __restrict__ lam_parts,
    float* __restrict__ out)
{
    __shared__ float lc[16][65];      // lam_c
    __shared__ u16 Sl[4][16][68];     // per-wave T: [nl][dc], 8.7 KB

    const int b = blockIdx.y, nblk = blockIdx.x, n0 = nblk * 16;
    const int t = threadIdx.x;
    const int h = t >> 6, lane = t & 63, li = lane & 15, lg = lane >> 4;
    const int ny = n0 >> 5;                  // image row of this n-block
    const int dshift = 31 - (n0 & 16);       // dc = ml + dshift - nl_local
    const int gbase = (n0 & 16) ? 0 : 1;     // 3 dc-tiles cover the band

    const u16* Vbb = Vb + (size_t)b * 64 * kM;
    u16* Sh = &Sl[h][0][0];

    // lam_c = sum of 16 partials
    for (int e = t; e < 1024; e += 256) {
        float s = 0.f;
#pragma unroll
        for (int p = 0; p < 16; ++p) s += lam_parts[(size_t)(p * kB + b) * 1024 + e];
        lc[e >> 6][e & 63] = s;
    }

    // Q fragment (16 rows)
    const u16* Qbase = Qb + ((size_t)(b * 4 + h) * kM + n0) * 32;
    bf16x8 qf = *(const bf16x8*)&Qbase[(size_t)li * 32 + lg * 8];

    // prefetch mrow=0 E slabs
    bf16x8 ra[3];
    {
        const int dr = 31 - ny;
#pragma unroll
        for (int g = 0; g < 3; ++g)
            ra[g] = *(const bf16x8*)&rpe_b[((size_t)dr * 64 + (gbase + g) * 16 + li) * 32 + lg * 8];
    }

    __syncthreads();   // lc ready

    // content term: acc[c] = Q @ lam_c
    f32x4 acc[4];
#pragma unroll
    for (int c = 0; c < 4; ++c) {
        bf16x8 cb;
#pragma unroll
        for (int j = 0; j < 8; ++j) {
            int k = lg * 8 + j;
            cb[j] = (k < 16) ? (short)f2b(lc[k][16 * c + li]) : (short)0;
        }
        f32x4 z = {0.f, 0.f, 0.f, 0.f};
        acc[c] = __builtin_amdgcn_mfma_f32_16x16x32_bf16(qf, cb, z, 0, 0, 0);
    }

    const int swr = li * 68;                       // S row base (u16)
    const int src0 = swr + 8 * lg + dshift - li;   // S read base (u16)

#pragma unroll 2
    for (int mrow = 0; mrow < 32; ++mrow) {
        // V fragments for this m-row (global, L2-hot)
        bf16x8 vf[4];
#pragma unroll
        for (int c = 0; c < 4; ++c)
            vf[c] = *(const bf16x8*)&Vbb[(size_t)(16 * c + li) * kM + mrow * 32 + lg * 8];

        // T^T: 3 dc-tiles
        f32x4 tq[3];
#pragma unroll
        for (int g = 0; g < 3; ++g) {
            f32x4 z = {0.f, 0.f, 0.f, 0.f};
            tq[g] = __builtin_amdgcn_mfma_f32_16x16x32_bf16(ra[g], qf, z, 0, 0, 0);
        }

        // prefetch next E slabs (land during S round-trip + PV)
        if (mrow < 31) {
            const int dr = mrow + 1 - ny + 31;
#pragma unroll
            for (int g = 0; g < 3; ++g)
                ra[g] = *(const bf16x8*)&rpe_b[((size_t)dr * 64 + (gbase + g) * 16 + li) * 32 + lg * 8];
        }

        // write T -> Sl[nl=li][dc], aligned 8B stores
#pragma unroll
        for (int g = 0; g < 3; ++g) {
            u16 pk[4];
#pragma unroll
            for (int reg = 0; reg < 4; ++reg) pk[reg] = f2b(tq[g][reg]);
            *(uint2*)&Sh[swr + (gbase + g) * 16 + 4 * lg] = *(const uint2*)pk;
        }

        asm volatile("" ::: "memory");   // keep S-reads after S-writes

        // read S A-frag: S[nl=li][ml=8lg+j] = T[li][ml + dshift - li]
        bf16x8 sa;
#pragma unroll
        for (int j = 0; j < 8; ++j)
            sa[j] = (short)Sh[src0 + j];

        __builtin_amdgcn_s_setprio(1);
#pragma unroll
        for (int c = 0; c < 4; ++c)
            acc[c] = __builtin_amdgcn_mfma_f32_16x16x32_bf16(sa, vf[c], acc[c], 0, 0, 0);
        __builtin_amdgcn_s_setprio(0);
    }

    // epilogue: n = n0 + 4lg+reg, v = 16c+li
    float* ob = out + ((size_t)b * kM + n0) * 256 + h * 64;
#pragma unroll
    for (int c = 0; c < 4; ++c)
#pragma unroll
        for (int reg = 0; reg < 4; ++reg)
            ob[(size_t)(4 * lg + reg) * 256 + 16 * c + li] = acc[c][reg];
}

}  // namespace

extern "C" void kernel_launch(void* const* d_in, const int* in_sizes, int n_in,
                              void* d_out, int out_size, void* d_ws, size_t ws_size,
                              hipStream_t stream) {
    const float* x   = (const float*)d_in[0];
    const float* Wq  = (const float*)d_in[1];
    const float* Wk  = (const float*)d_in[2];
    const float* Wv  = (const float*)d_in[3];
    const float* gq  = (const float*)d_in[4];
    const float* bq  = (const float*)d_in[5];
    const float* mq  = (const float*)d_in[6];
    const float* vq  = (const float*)d_in[7];
    const float* gv  = (const float*)d_in[8];
    const float* bv  = (const float*)d_in[9];
    const float* mv  = (const float*)d_in[10];
    const float* vv  = (const float*)d_in[11];
    const float* rpe = (const float*)d_in[12];
    float* out = (float*)d_out;

    float* Kf        = (float*)d_ws;                                 // 16*16*1024 f32
    float* lam_parts = Kf + (size_t)16 * 16 * 1024;                  // 16*16*1024 f32
    float* bbuf      = lam_parts + (size_t)16 * 16 * 1024;           // 144 f32
    u16*   Qb        = (u16*)(bbuf + 256);                           // 16*4*1024*32
    u16*   Vb        = Qb + (size_t)16 * 4 * 1024 * 32;              // 16*64*1024
    u16*   rpe_b     = Vb + (size_t)16 * 64 * 1024;                  // 63*64*32
    u16*   Wb        = rpe_b + (size_t)63 * 64 * 32;                 // 144*256

    k_prep<<<72, 256, 0, stream>>>(Wq, Wk, Wv, gq, bq, mq, vq, gv, bv, mv, vv,
                                   rpe, Wb, bbuf, rpe_b);
    k_qkv<<<dim3(64, 16), 256, 0, stream>>>(x, Wb, bbuf, Qb, Kf, Vb);
    k_lam<<<dim3(16, 16), 256, 0, stream>>>(Kf, Vb, lam_parts);
    k_attn<<<dim3(64, 16), 256, 0, stream>>>(Qb, Vb, rpe_b, lam_parts, out);
}

// Round 8
// 162.190 us; speedup vs baseline: 1.1929x; 1.1929x over previous
//
#include <hip/hip_runtime.h>
#include <math.h>

namespace {
typedef unsigned short u16;
typedef __attribute__((ext_vector_type(4))) float f32x4;
typedef __attribute__((ext_vector_type(8))) short bf16x8;

constexpr int kB  = 16;
constexpr int kC  = 256;
constexpr int kM  = 1024;

__device__ inline u16 f2b(float f) {
    union { float f; unsigned u; } un; un.f = f;
    unsigned r = un.u + 0x7FFF + ((un.u >> 16) & 1);
    return (u16)(r >> 16);
}

// ---------------------------------------------------------------------------
// K0: blocks 0..8: pack W (BN folded) -> Wb bf16 [144][256], bias bb f32
//     blocks 9..71: rpe f32 [63][63][16] -> rpe_b bf16 [63dr][64dc][32k]
// ---------------------------------------------------------------------------
__global__ __launch_bounds__(256) void k_prep(
    const float* __restrict__ Wq, const float* __restrict__ Wk,
    const float* __restrict__ Wv,
    const float* __restrict__ gq, const float* __restrict__ bq,
    const float* __restrict__ mq, const float* __restrict__ vq,
    const float* __restrict__ gv, const float* __restrict__ bv,
    const float* __restrict__ mv, const float* __restrict__ vv,
    const float* __restrict__ rpe,
    u16* __restrict__ Wb, float* __restrict__ bb, u16* __restrict__ rpe_b)
{
    const int bid = blockIdx.x;
    const int t = threadIdx.x;
    if (bid < 9) {
        const int oc = bid * 16 + (t >> 4);
        const int c0 = (t & 15) * 16;
        float s, bias;
        const float* wrow;
        if (oc < 64)      { float inv = rsqrtf(vq[oc] + 1e-5f); s = inv * gq[oc]; bias = bq[oc] - mq[oc] * s; wrow = Wq + (size_t)oc * kC; }
        else if (oc < 80) { s = 1.f; bias = 0.f; wrow = Wk + (size_t)(oc - 64) * kC; }
        else              { int i2 = oc - 80; float inv = rsqrtf(vv[i2] + 1e-5f); s = inv * gv[i2]; bias = bv[i2] - mv[i2] * s; wrow = Wv + (size_t)i2 * kC; }
#pragma unroll
        for (int cc = 0; cc < 16; ++cc)
            Wb[(size_t)oc * kC + c0 + cc] = f2b(wrow[c0 + cc] * s);
        if (c0 == 0) bb[oc] = bias;
    } else {
        const int dr = bid - 9;
        for (int e = t; e < 2048; e += 256) {
            int dc = e >> 5, k = e & 31;
            float v = (dc < 63 && k < 16) ? rpe[((size_t)dr * 63 + dc) * 16 + k] : 0.f;
            rpe_b[((size_t)dr * 64 + dc) * 32 + k] = f2b(v);
        }
    }
}

// ---------------------------------------------------------------------------
// K1 (MFMA): conv1x1, 16-m tiles, X staged as bf16 TRANSPOSED [m][c] so
// B-frags are single ds_read_b128 (no per-chunk f32->bf16 pack).
// grid (64 mtile, 16 b), block 256 (4 waves; w0:{Q0,Q1,Q2} w1:{Q3,K} w2:{V0,V1} w3:{V2,V3})
// ---------------------------------------------------------------------------
__global__ __launch_bounds__(256) void k_qkv(
    const float* __restrict__ x, const u16* __restrict__ Wb,
    const float* __restrict__ bb,
    u16* __restrict__ Qb, float* __restrict__ Kf, u16* __restrict__ Vb)
{
    __shared__ u16 Xs[16][264];   // [m][c] bf16, 8.4 KB

    const int b  = blockIdx.y;
    const int m0 = blockIdx.x * 16;
    const int t  = threadIdx.x;
    const int w  = t >> 6, lane = t & 63, li = lane & 15, lg = lane >> 4;

    // stage + transpose + convert: 1024 float4 reads, 16 f2b per thread
#pragma unroll
    for (int j = 0; j < 4; ++j) {
        int e = t + 256 * j;
        int c = e >> 2, m4 = (e & 3) * 4;
        float4 xv = *(const float4*)&x[(size_t)(b * kC + c) * kM + m0 + m4];
        Xs[m4 + 0][c] = f2b(xv.x);
        Xs[m4 + 1][c] = f2b(xv.y);
        Xs[m4 + 2][c] = f2b(xv.z);
        Xs[m4 + 3][c] = f2b(xv.w);
    }
    __syncthreads();

    const int nt = (w == 0) ? 3 : 2;
    const int t0 = (w == 0) ? 0 : 2 * w + 1;

    f32x4 acc[3];
#pragma unroll
    for (int i = 0; i < 3; ++i) acc[i] = (f32x4){0.f, 0.f, 0.f, 0.f};

    for (int ch = 0; ch < 8; ++ch) {
        const int c0 = ch * 32 + lg * 8;
        bf16x8 bfr = *(const bf16x8*)&Xs[li][c0];       // aligned b128
        for (int i = 0; i < nt; ++i) {
            bf16x8 afr = *(const bf16x8*)&Wb[(size_t)((t0 + i) * 16 + li) * kC + c0];
            acc[i] = __builtin_amdgcn_mfma_f32_16x16x32_bf16(afr, bfr, acc[i], 0, 0, 0);
        }
    }

    const int m = m0 + li;
    for (int i = 0; i < nt; ++i) {
        const int tile = t0 + i;
        const int ocb = tile * 16 + lg * 4;
        float o[4];
#pragma unroll
        for (int reg = 0; reg < 4; ++reg) o[reg] = acc[i][reg] + bb[ocb + reg];
        if (tile < 4) {                       // Q tile: h=tile, k=lg*4+reg
            u16 pk[4];
#pragma unroll
            for (int reg = 0; reg < 4; ++reg) pk[reg] = f2b(o[reg]);
            u16* qp = Qb + ((size_t)(b * 4 + tile) * kM + m) * 32;
            *(uint2*)&qp[lg * 4] = *(const uint2*)pk;
            uint2 z; z.x = 0u; z.y = 0u;
            *(uint2*)&qp[16 + lg * 4] = z;
        } else if (tile == 4) {               // K f32
#pragma unroll
            for (int reg = 0; reg < 4; ++reg)
                Kf[(size_t)(b * 16 + lg * 4 + reg) * kM + m] = o[reg];
        } else {                              // V
            const int vb = (tile - 5) * 16 + lg * 4;
#pragma unroll
            for (int reg = 0; reg < 4; ++reg)
                Vb[(size_t)(b * 64 + vb + reg) * kM + m] = f2b(o[reg]);
        }
    }
}

// ---------------------------------------------------------------------------
// K2 (MFMA): softmax_k(K) then lam_c[k][v] = sum_m sK[m,k] V[m,v], written
// FINAL as lamb bf16 [b][64v][32k] (k>=16 zero).  grid 16 (1/batch), block 512.
// waves: (ms = m-half of 512, vt = v-tile of 16)
// ---------------------------------------------------------------------------
__global__ __launch_bounds__(512) void k_lam(
    const float* __restrict__ Kf, const u16* __restrict__ Vb,
    u16* __restrict__ lamb)
{
    __shared__ u16 sk[16][1048];          // softmaxed K^T: [k][m], 33.5 KB
    __shared__ float red[2][4][16][16];   // partial acc, 8 KB

    const int b = blockIdx.x, t = threadIdx.x;

#pragma unroll
    for (int j = 0; j < 2; ++j) {
        const int m = t + 512 * j;
        float vals[16];
        float mx = -1e30f;
#pragma unroll
        for (int k = 0; k < 16; ++k) { vals[k] = Kf[(size_t)(b * 16 + k) * kM + m]; mx = fmaxf(mx, vals[k]); }
        float sum = 0.f;
#pragma unroll
        for (int k = 0; k < 16; ++k) { vals[k] = __expf(vals[k] - mx); sum += vals[k]; }
        const float inv = 1.f / sum;
#pragma unroll
        for (int k = 0; k < 16; ++k) sk[k][m] = f2b(vals[k] * inv);
    }
    __syncthreads();

    const int w = t >> 6, lane = t & 63, li = lane & 15, lg = lane >> 4;
    const int ms = w >> 2, vt = w & 3;
    f32x4 acc = {0.f, 0.f, 0.f, 0.f};
    for (int ck = 0; ck < 16; ++ck) {
        const int mch = ms * 512 + ck * 32 + lg * 8;
        bf16x8 af = *(const bf16x8*)&sk[li][mch];                              // A[k=li][m]
        bf16x8 bf_ = *(const bf16x8*)&Vb[(size_t)(b * 64 + vt * 16 + li) * kM + mch];  // B[m][v=li]
        acc = __builtin_amdgcn_mfma_f32_16x16x32_bf16(af, bf_, acc, 0, 0, 0);
    }
#pragma unroll
    for (int reg = 0; reg < 4; ++reg)
        red[ms][vt][lg * 4 + reg][li] = acc[reg];
    __syncthreads();

    for (int e = t; e < 2048; e += 512) {
        int v = e >> 5, k = e & 31;
        u16 o = 0;
        if (k < 16) o = f2b(red[0][v >> 4][k][v & 15] + red[1][v >> 4][k][v & 15]);
        lamb[(size_t)b * 2048 + v * 32 + k] = o;
    }
}

// ---------------------------------------------------------------------------
// K3 (MFMA, barrier-free loop): out = Q@lam_c + position for 32 n-rows.
// grid (32 nblk, 16 b), block 256 = 4 waves = 4 heads.  E and V fragments
// direct from L2-resident global, PREFETCHED one full iteration ahead; LDS
// only for the per-wave S round-trip (aligned b64 writes, u16 reads).
// ---------------------------------------------------------------------------
__global__ __launch_bounds__(256, 2) void k_attn(
    const u16* __restrict__ Qb, const u16* __restrict__ Vb,
    const u16* __restrict__ rpe_b, const u16* __restrict__ lamb,
    float* __restrict__ out)
{
    __shared__ u16 Sl[4][32][72];     // per-wave T: [nl][dc], 18.4 KB

    const int b = blockIdx.y, nblk = blockIdx.x, n0 = nblk * 32;
    const int t = threadIdx.x;
    const int h = t >> 6, lane = t & 63, li = lane & 15, lg = lane >> 4;

    const u16* Vbb = Vb + (size_t)b * 64 * kM;
    u16* Sh = &Sl[h][0][0];

    // Q fragments (32 rows -> 2 frags)
    const u16* Qbase = Qb + ((size_t)(b * 4 + h) * kM + n0) * 32;
    bf16x8 qf[2];
    qf[0] = *(const bf16x8*)&Qbase[(size_t)li * 32 + lg * 8];
    qf[1] = *(const bf16x8*)&Qbase[(size_t)(16 + li) * 32 + lg * 8];

    // content term from precomputed bf16 lamb (L2-hot, tiny)
    f32x4 acc[2][4];
    const u16* lb = lamb + (size_t)b * 2048;
#pragma unroll
    for (int c = 0; c < 4; ++c) {
        bf16x8 cb = *(const bf16x8*)&lb[(size_t)(16 * c + li) * 32 + lg * 8];
        f32x4 z = {0.f, 0.f, 0.f, 0.f};
        acc[0][c] = __builtin_amdgcn_mfma_f32_16x16x32_bf16(qf[0], cb, z, 0, 0, 0);
        acc[1][c] = __builtin_amdgcn_mfma_f32_16x16x32_bf16(qf[1], cb, z, 0, 0, 0);
    }

    // preload mrow 0 fragments
    bf16x8 ra[4], vf[4];
    {
        const int dr = 31 - nblk;
#pragma unroll
        for (int g = 0; g < 4; ++g)
            ra[g] = *(const bf16x8*)&rpe_b[((size_t)dr * 64 + g * 16 + li) * 32 + lg * 8];
#pragma unroll
        for (int c = 0; c < 4; ++c)
            vf[c] = *(const bf16x8*)&Vbb[(size_t)(16 * c + li) * kM + lg * 8];
    }

#pragma unroll 2
    for (int mrow = 0; mrow < 32; ++mrow) {
        // issue next-iter loads FIRST (hide under T^T + S round-trip + PV)
        bf16x8 ran[4], vfn[4];
        if (mrow < 31) {
            const int dr = mrow + 1 - nblk + 31;
            const int mb2 = (mrow + 1) * 32;
#pragma unroll
            for (int g = 0; g < 4; ++g)
                ran[g] = *(const bf16x8*)&rpe_b[((size_t)dr * 64 + g * 16 + li) * 32 + lg * 8];
#pragma unroll
            for (int c = 0; c < 4; ++c)
                vfn[c] = *(const bf16x8*)&Vbb[(size_t)(16 * c + li) * kM + mb2 + lg * 8];
        }

        // T^T: 4 dc-tiles x 2 n-frags
        f32x4 tq[4][2];
#pragma unroll
        for (int g = 0; g < 4; ++g) {
            f32x4 z = {0.f, 0.f, 0.f, 0.f};
            tq[g][0] = __builtin_amdgcn_mfma_f32_16x16x32_bf16(ra[g], qf[0], z, 0, 0, 0);
            tq[g][1] = __builtin_amdgcn_mfma_f32_16x16x32_bf16(ra[g], qf[1], z, 0, 0, 0);
        }

        // write T[nl][dc], aligned 8B stores (row = 16r+li, col = 16g+4lg)
#pragma unroll
        for (int g = 0; g < 4; ++g)
#pragma unroll
            for (int r = 0; r < 2; ++r) {
                u16 pk[4];
#pragma unroll
                for (int reg = 0; reg < 4; ++reg) pk[reg] = f2b(tq[g][r][reg]);
                *(uint2*)&Sh[(size_t)(16 * r + li) * 72 + 16 * g + 4 * lg] = *(const uint2*)pk;
            }

        asm volatile("" ::: "memory");   // keep S-reads after S-writes

        // read S A-frags and PV
#pragma unroll
        for (int r = 0; r < 2; ++r) {
            const int base = (16 * r + li) * 72 + 8 * lg + 31 - 16 * r - li;
            bf16x8 sa;
#pragma unroll
            for (int j = 0; j < 8; ++j) sa[j] = (short)Sh[base + j];
            __builtin_amdgcn_s_setprio(1);
#pragma unroll
            for (int c = 0; c < 4; ++c)
                acc[r][c] = __builtin_amdgcn_mfma_f32_16x16x32_bf16(sa, vf[c], acc[r][c], 0, 0, 0);
            __builtin_amdgcn_s_setprio(0);
        }

        if (mrow < 31) {
#pragma unroll
            for (int g = 0; g < 4; ++g) ra[g] = ran[g];
#pragma unroll
            for (int c = 0; c < 4; ++c) vf[c] = vfn[c];
        }
    }

    // epilogue: n = n0 + 16r + 4lg + reg, v = 16c + li
    float* ob = out + ((size_t)b * kM + n0) * 256 + h * 64;
#pragma unroll
    for (int r = 0; r < 2; ++r)
#pragma unroll
        for (int c = 0; c < 4; ++c)
#pragma unroll
            for (int reg = 0; reg < 4; ++reg)
                ob[(size_t)(16 * r + 4 * lg + reg) * 256 + 16 * c + li] = acc[r][c][reg];
}

}  // namespace

extern "C" void kernel_launch(void* const* d_in, const int* in_sizes, int n_in,
                              void* d_out, int out_size, void* d_ws, size_t ws_size,
                              hipStream_t stream) {
    const float* x   = (const float*)d_in[0];
    const float* Wq  = (const float*)d_in[1];
    const float* Wk  = (const float*)d_in[2];
    const float* Wv  = (const float*)d_in[3];
    const float* gq  = (const float*)d_in[4];
    const float* bq  = (const float*)d_in[5];
    const float* mq  = (const float*)d_in[6];
    const float* vq  = (const float*)d_in[7];
    const float* gv  = (const float*)d_in[8];
    const float* bv  = (const float*)d_in[9];
    const float* mv  = (const float*)d_in[10];
    const float* vv  = (const float*)d_in[11];
    const float* rpe = (const float*)d_in[12];
    float* out = (float*)d_out;

    float* Kf    = (float*)d_ws;                            // 16*16*1024 f32
    float* bbuf  = Kf + (size_t)16 * 16 * 1024;             // 256 f32
    u16*   Qb    = (u16*)(bbuf + 256);                      // 16*4*1024*32
    u16*   Vb    = Qb + (size_t)16 * 4 * 1024 * 32;         // 16*64*1024
    u16*   rpe_b = Vb + (size_t)16 * 64 * 1024;             // 63*64*32
    u16*   Wb    = rpe_b + (size_t)63 * 64 * 32;            // 144*256
    u16*   lamb  = Wb + (size_t)144 * 256;                  // 16*64*32

    k_prep<<<72, 256, 0, stream>>>(Wq, Wk, Wv, gq, bq, mq, vq, gv, bv, mv, vv,
                                   rpe, Wb, bbuf, rpe_b);
    k_qkv<<<dim3(64, 16), 256, 0, stream>>>(x, Wb, bbuf, Qb, Kf, Vb);
    k_lam<<<16, 512, 0, stream>>>(Kf, Vb, lamb);
    k_attn<<<dim3(32, 16), 256, 0, stream>>>(Qb, Vb, rpe_b, lamb, out);
}